// Round 1
// baseline (298.426 us; speedup 1.0000x reference)
//
#include <hip/hip_runtime.h>
#include <cstdint>
#include <cstddef>

// Block-diagonal GRU on MI355X (gfx950), bf16 MFMA path.
// B=8192, IN=1024, H=2048, NB=8, BS=256, 3H=6144.

typedef __attribute__((ext_vector_type(8))) short bf16x8;
typedef __attribute__((ext_vector_type(4))) float f32x4;

__device__ __forceinline__ unsigned short f2bf(float f) {
    uint32_t u = __float_as_uint(f);
    u += 0x7FFFu + ((u >> 16) & 1u);   // round-to-nearest-even
    return (unsigned short)(u >> 16);
}
__device__ __forceinline__ float bf2f(unsigned short b) {
    return __uint_as_float(((uint32_t)b) << 16);
}

__device__ __forceinline__ void gload16(const void* g, void* l) {
    __builtin_amdgcn_global_load_lds(
        (const __attribute__((address_space(1))) void*)g,
        (__attribute__((address_space(3))) void*)l,
        16, 0, 0);
}

__device__ __forceinline__ float sigmoidf_(float x) {
    return 1.0f / (1.0f + __expf(-x));
}
__device__ __forceinline__ float tanhf_(float x) {
    float e = __expf(-2.0f * fabsf(x));
    float t = (1.0f - e) / (1.0f + e);
    return copysignf(t, x);
}

// ---------------------------------------------------------------- casts
__global__ __launch_bounds__(256)
void cast_f32_to_bf16(const float* __restrict__ s, unsigned short* __restrict__ d, int n4) {
    int i = blockIdx.x * 256 + threadIdx.x;
    if (i >= n4) return;
    const float4 v = *reinterpret_cast<const float4*>(s + (size_t)i * 4);
    ushort4 o;
    o.x = f2bf(v.x); o.y = f2bf(v.y); o.z = f2bf(v.z); o.w = f2bf(v.w);
    *reinterpret_cast<ushort4*>(d + (size_t)i * 4) = o;
}

// ---------------------------------------------------------------- GEMM1: wx = x @ W_ir^T + b_ir_lin + b_ir  (bf16 out)
// A [8192][1024] bf16, Bt [6144][1024] bf16 (B^T layout), C [8192][6144] bf16
__global__ __launch_bounds__(256)
void gemm_wx_kernel(const unsigned short* __restrict__ A,
                    const unsigned short* __restrict__ Bt,
                    const float* __restrict__ bias0,
                    const float* __restrict__ bias1,
                    unsigned short* __restrict__ C) {
    constexpr int N = 6144, K = 1024;
    __shared__ unsigned short As[128 * 32];
    __shared__ unsigned short Bs[128 * 32];

    const int tid  = threadIdx.x;
    const int lane = tid & 63;
    const int w    = tid >> 6;
    const int wr   = (w >> 1) * 64;   // wave row offset in tile
    const int wc   = (w & 1) * 64;    // wave col offset in tile
    const int bm = blockIdx.y * 128;
    const int bn = blockIdx.x * 128;

    const int srow = tid >> 2;        // 0..63
    const int scol = (tid & 3) * 8;   // k element offset

    const unsigned short* ag0 = A + (size_t)(bm + srow) * K + scol;
    const unsigned short* ag1 = ag0 + (size_t)64 * K;
    const unsigned short* bg0 = Bt + (size_t)(bn + srow) * K + scol;
    const unsigned short* bg1 = bg0 + (size_t)64 * K;
    unsigned short* la0 = &As[srow * 32 + scol];
    unsigned short* la1 = &As[(64 + srow) * 32 + scol];
    unsigned short* lb0 = &Bs[srow * 32 + scol];
    unsigned short* lb1 = &Bs[(64 + srow) * 32 + scol];

    const int fr = lane & 15;
    const int k0 = (lane >> 4) * 8;

    f32x4 acc[4][4] = {};

    for (int kt = 0; kt < K; kt += 32) {
        __syncthreads();                  // previous tile consumed
        gload16(ag0 + kt, la0);
        gload16(ag1 + kt, la1);
        gload16(bg0 + kt, lb0);
        gload16(bg1 + kt, lb1);
        asm volatile("s_waitcnt vmcnt(0)" ::: "memory");
        __syncthreads();                  // tile visible to all waves

        bf16x8 af[4], bv[4];
        #pragma unroll
        for (int m = 0; m < 4; ++m)
            af[m] = *(const bf16x8*)&As[(wr + m * 16 + fr) * 32 + k0];
        #pragma unroll
        for (int n = 0; n < 4; ++n)
            bv[n] = *(const bf16x8*)&Bs[(wc + n * 16 + fr) * 32 + k0];
        #pragma unroll
        for (int m = 0; m < 4; ++m)
            #pragma unroll
            for (int n = 0; n < 4; ++n)
                acc[m][n] = __builtin_amdgcn_mfma_f32_16x16x32_bf16(af[m], bv[n], acc[m][n], 0, 0, 0);
    }

    const int rbase = (lane >> 4) * 4;
    #pragma unroll
    for (int n = 0; n < 4; ++n) {
        const int col = bn + wc + n * 16 + fr;
        const float bb = bias0[col] + bias1[col];
        #pragma unroll
        for (int m = 0; m < 4; ++m) {
            #pragma unroll
            for (int r = 0; r < 4; ++r) {
                const int row = bm + wr + m * 16 + rbase + r;
                C[(size_t)row * N + col] = f2bf(acc[m][n][r] + bb);
            }
        }
    }
}

// ---------------------------------------------------------------- GEMM2 + gates
// Per 128x64 output tile of h_new: accumulate 3 gate strips (r,z,n) of the
// block-diagonal projection wh = hb @ W_h[k]^T over K=256, then fuse gates.
__global__ __launch_bounds__(256)
void gru_gate_kernel(const unsigned short* __restrict__ Hb,   // [8192][2048] bf16
                     const unsigned short* __restrict__ Wh,   // [8][768][256] bf16
                     const unsigned short* __restrict__ WX,   // [8192][6144] bf16
                     const float* __restrict__ b_hr,          // [6144]
                     const float* __restrict__ Hf,            // [8192][2048] f32
                     float* __restrict__ out) {               // [8192][2048] f32
    constexpr int H = 2048, N3 = 6144, K = 256;
    __shared__ unsigned short As[128 * 32];
    __shared__ unsigned short Bs[192 * 32];

    const int tid  = threadIdx.x;
    const int lane = tid & 63;
    const int w    = tid >> 6;            // wave 0..3 -> rows w*32..w*32+31
    const int bm = blockIdx.y * 128;
    const int colbase = blockIdx.x * 64;  // h-column base (0..2047)
    const int kb  = colbase >> 8;         // diagonal block index
    const int lcb = colbase & 255;        // local column base within block

    const int srow = tid >> 2;
    const int scol = (tid & 3) * 8;

    const unsigned short* ag = Hb + (size_t)(bm + srow) * H + kb * 256 + scol;
    const unsigned short* wb = Wh + (size_t)kb * 768 * 256;

    const int fr = lane & 15;
    const int k0 = (lane >> 4) * 8;

    f32x4 acc[3][2][4] = {};

    for (int kt = 0; kt < K; kt += 32) {
        __syncthreads();
        gload16(ag + kt, &As[srow * 32 + scol]);
        gload16(ag + (size_t)64 * H + kt, &As[(64 + srow) * 32 + scol]);
        #pragma unroll
        for (int i = 0; i < 3; ++i) {
            // LDS row i*64+srow holds W_h[k] row (i*256 + lcb + srow)
            const unsigned short* src = wb + (size_t)(i * 256 + lcb + srow) * 256 + kt + scol;
            gload16(src, &Bs[(i * 64 + srow) * 32 + scol]);
        }
        asm volatile("s_waitcnt vmcnt(0)" ::: "memory");
        __syncthreads();

        bf16x8 af[2], bv[3][4];
        #pragma unroll
        for (int m = 0; m < 2; ++m)
            af[m] = *(const bf16x8*)&As[(w * 32 + m * 16 + fr) * 32 + k0];
        #pragma unroll
        for (int s = 0; s < 3; ++s)
            #pragma unroll
            for (int n = 0; n < 4; ++n)
                bv[s][n] = *(const bf16x8*)&Bs[(s * 64 + n * 16 + fr) * 32 + k0];
        #pragma unroll
        for (int s = 0; s < 3; ++s)
            #pragma unroll
            for (int m = 0; m < 2; ++m)
                #pragma unroll
                for (int n = 0; n < 4; ++n)
                    acc[s][m][n] = __builtin_amdgcn_mfma_f32_16x16x32_bf16(af[m], bv[s][n], acc[s][m][n], 0, 0, 0);
    }

    const int rbase = (lane >> 4) * 4;
    #pragma unroll
    for (int n = 0; n < 4; ++n) {
        const int lcol = lcb + n * 16 + fr;       // 0..255 within block
        const int hcol = colbase + n * 16 + fr;   // 0..2047
        const float br  = b_hr[kb * 768 + lcol];
        const float bz  = b_hr[kb * 768 + 256 + lcol];
        const float bnn = b_hr[kb * 768 + 512 + lcol];
        #pragma unroll
        for (int m = 0; m < 2; ++m) {
            #pragma unroll
            for (int r = 0; r < 4; ++r) {
                const int row = bm + w * 32 + m * 16 + rbase + r;
                const size_t wxoff = (size_t)row * N3 + hcol;
                const float wxr = bf2f(WX[wxoff]);
                const float wxz = bf2f(WX[wxoff + H]);
                const float wxn = bf2f(WX[wxoff + 2 * H]);
                const float whr = acc[0][m][n][r] + br;
                const float whz = acc[1][m][n][r] + bz;
                const float whn = acc[2][m][n][r] + bnn;
                const float rg = sigmoidf_(wxr + whr);
                const float zg = sigmoidf_(wxz + whz);
                const float ng = tanhf_(wxn + rg * whn);
                const float hv = Hf[(size_t)row * H + hcol];
                out[(size_t)row * H + hcol] = (1.0f - zg) * hv + zg * ng;
            }
        }
    }
}

// ---------------------------------------------------------------- launch
extern "C" void kernel_launch(void* const* d_in, const int* in_sizes, int n_in,
                              void* d_out, int out_size, void* d_ws, size_t ws_size,
                              hipStream_t stream) {
    const float* x        = (const float*)d_in[0];  // [8192][1024]
    const float* h        = (const float*)d_in[1];  // [8192][2048]
    const float* W_ir     = (const float*)d_in[2];  // [6144][1024]
    const float* b_ir_lin = (const float*)d_in[3];  // [6144]
    const float* b_ir     = (const float*)d_in[4];  // [6144]
    const float* W_h      = (const float*)d_in[5];  // [8][768][256]
    const float* b_hr     = (const float*)d_in[6];  // [6144]
    float* out = (float*)d_out;                     // [8192][2048]

    char* ws = (char*)d_ws;
    unsigned short* xb   = (unsigned short*)(ws);                    // 16,777,216 B
    unsigned short* wirb = (unsigned short*)(ws + 16777216);         // 12,582,912 B
    unsigned short* hb   = (unsigned short*)(ws + 29360128);         // 33,554,432 B
    unsigned short* whb  = (unsigned short*)(ws + 62914560);         //  3,145,728 B
    unsigned short* wx   = (unsigned short*)(ws + 66060288);         // 100,663,296 B (end ~159 MiB)

    cast_f32_to_bf16<<<8192,  256, 0, stream>>>(x,    xb,   2097152);
    cast_f32_to_bf16<<<6144,  256, 0, stream>>>(W_ir, wirb, 1572864);
    cast_f32_to_bf16<<<16384, 256, 0, stream>>>(h,    hb,   4194304);
    cast_f32_to_bf16<<<1536,  256, 0, stream>>>(W_h,  whb,  393216);

    dim3 g1(48, 64);   // N/128 x M/128
    gemm_wx_kernel<<<g1, 256, 0, stream>>>(xb, wirb, b_ir_lin, b_ir, wx);

    dim3 g2(32, 64);   // H/64 x M/128
    gru_gate_kernel<<<g2, 256, 0, stream>>>(hb, whb, wx, b_hr, h, out);
}

// Round 2
// 289.573 us; speedup vs baseline: 1.0306x; 1.0306x over previous
//
#include <hip/hip_runtime.h>
#include <cstdint>
#include <cstddef>

// Block-diagonal GRU on MI355X (gfx950), bf16 MFMA path.
// B=8192, IN=1024, H=2048, NB=8, BS=256, 3H=6144.

typedef __attribute__((ext_vector_type(8))) short bf16x8;
typedef __attribute__((ext_vector_type(4))) float f32x4;

__device__ __forceinline__ unsigned short f2bf(float f) {
    uint32_t u = __float_as_uint(f);
    u += 0x7FFFu + ((u >> 16) & 1u);   // round-to-nearest-even
    return (unsigned short)(u >> 16);
}
__device__ __forceinline__ float bf2f(unsigned short b) {
    return __uint_as_float(((uint32_t)b) << 16);
}

__device__ __forceinline__ void gload16(const void* g, void* l) {
    __builtin_amdgcn_global_load_lds(
        (const __attribute__((address_space(1))) void*)g,
        (__attribute__((address_space(3))) void*)l,
        16, 0, 0);
}

__device__ __forceinline__ float sigmoidf_(float x) {
    return 1.0f / (1.0f + __expf(-x));
}
__device__ __forceinline__ float tanhf_(float x) {
    float e = __expf(-2.0f * fabsf(x));
    float t = (1.0f - e) / (1.0f + e);
    return copysignf(t, x);
}

// ---------------------------------------------------------------- casts
__global__ __launch_bounds__(256)
void cast_f32_to_bf16(const float* __restrict__ s, unsigned short* __restrict__ d, int n4) {
    int i = blockIdx.x * 256 + threadIdx.x;
    if (i >= n4) return;
    const float4 v = *reinterpret_cast<const float4*>(s + (size_t)i * 4);
    ushort4 o;
    o.x = f2bf(v.x); o.y = f2bf(v.y); o.z = f2bf(v.z); o.w = f2bf(v.w);
    *reinterpret_cast<ushort4*>(d + (size_t)i * 4) = o;
}

// ---------------------------------------------------------------- GEMM1 (phased, counted vmcnt, T2 swizzle)
// wx = x @ W_ir^T + b_ir_lin + b_ir  (bf16 out)
// A [8192][1024] bf16, Bt [6144][1024] bf16 (B^T layout), C [8192][6144] bf16
// BM=128 BN=256 BK=64, 8 waves (2M x 4N), wave tile 64x64.
// LDS: 3 slots x (A 128x64 + B 256x64) bf16 = 144 KiB.
// Slot rotation: compute t from slot t%3, stage t+2 into slot (t+2)%3
// (last read at K-tile t-1 -> race-free). vmcnt(6) per K-tile, never 0
// until the drain at t=14.
#define STAGE3_0(kt, s) do { \
    gload16(sA0 + (size_t)(kt) * 64, As + (s) * 8192 + doff); \
    gload16(sA1 + (size_t)(kt) * 64, As + (s) * 8192 + 4096 + doff); \
    gload16(sB0 + (size_t)(kt) * 64, Bs + (s) * 16384 + doff); \
} while (0)
#define STAGE3_1(kt, s) do { \
    gload16(sB1 + (size_t)(kt) * 64, Bs + (s) * 16384 + 4096 + doff); \
    gload16(sB2 + (size_t)(kt) * 64, Bs + (s) * 16384 + 8192 + doff); \
    gload16(sB3 + (size_t)(kt) * 64, Bs + (s) * 16384 + 12288 + doff); \
} while (0)

__global__ __launch_bounds__(512, 2)
void gemm_wx_8phase(const unsigned short* __restrict__ A,
                    const unsigned short* __restrict__ Bt,
                    const float* __restrict__ bias0,
                    const float* __restrict__ bias1,
                    unsigned short* __restrict__ C) {
    constexpr int N = 6144, K = 1024;
    constexpr int NKT = 16;   // K / 64
    __shared__ unsigned short lds[3 * 8192 + 3 * 16384];
    unsigned short* const As = lds;              // 3 slots of 128*64
    unsigned short* const Bs = lds + 3 * 8192;   // 3 slots of 256*64

    const int tid  = threadIdx.x;
    const int lane = tid & 63;
    const int w    = tid >> 6;
    const int wm   = w >> 2;      // 0..1
    const int wn   = w & 3;       // 0..3

    // XCD-aware swizzle: 1536 blocks, 1536 % 8 == 0 -> simple bijection.
    // bm-major within each XCD chunk so the A-panel (8 tiles, 2 MB) is L2-hot.
    const int bid = blockIdx.x;
    const int swz = (bid & 7) * 192 + (bid >> 3);
    const int bm  = (swz / 24) * 128;
    const int bn  = (swz % 24) * 256;

    // ---- staging source addresses (inverse-swizzled global, linear LDS dest)
    // dest byte d = j*8192 + tid*16 within slot; row = d>>7;
    // logical byte-in-row = (d & 127) ^ ((row & 7) << 4)
    const int srow   = tid >> 3;                         // 0..63
    const int mask16 = (srow & 7) << 4;
    const int scol   = (((tid & 7) << 4) ^ mask16) >> 1; // element col, 8-aligned
    const unsigned short* sA0 = A  + (size_t)(bm + srow)       * K + scol;
    const unsigned short* sA1 = A  + (size_t)(bm + 64 + srow)  * K + scol;
    const unsigned short* sB0 = Bt + (size_t)(bn + srow)       * K + scol;
    const unsigned short* sB1 = Bt + (size_t)(bn + 64 + srow)  * K + scol;
    const unsigned short* sB2 = Bt + (size_t)(bn + 128 + srow) * K + scol;
    const unsigned short* sB3 = Bt + (size_t)(bn + 192 + srow) * K + scol;
    const int doff = tid * 8;    // element offset within a 4096-elem (8KB) half

    // ---- fragment read offsets (swizzled LDS reads)
    const int fr  = lane & 15;
    const int k0e = (lane >> 4) * 8;            // k element offset
    const int mfr = (fr & 7) << 4;
    const int kb0 = ((k0e * 2) ^ mfr) >> 1;         // kk=0, element offset in row
    const int kb1 = (((k0e * 2) + 64) ^ mfr) >> 1;  // kk=1
    const int ar0 = (wm * 64 + fr) * 64;        // A row base (elements), +1024/m
    const int br0 = (wn * 64 + fr) * 64;        // B row base

    f32x4 acc[4][4] = {};

    // ---- prologue: K-tiles 0,1 -> slots 0,1
    STAGE3_0(0, 0); STAGE3_1(0, 0);
    STAGE3_0(1, 1); STAGE3_1(1, 1);
    asm volatile("s_waitcnt vmcnt(6)" ::: "memory");   // K-tile 0 landed
    __builtin_amdgcn_s_barrier();

    int slot = 0, sslot = 2;
    for (int t = 0; t < NKT; ++t) {
        const unsigned short* aS = As + slot * 8192;
        const unsigned short* bS = Bs + slot * 16384;
        bf16x8 av[4], bv[4];

        // ---------------- phase 0 (kk = 0)
        #pragma unroll
        for (int m = 0; m < 4; ++m)
            av[m] = *(const bf16x8*)(aS + ar0 + m * 1024 + kb0);
        #pragma unroll
        for (int n = 0; n < 4; ++n)
            bv[n] = *(const bf16x8*)(bS + br0 + n * 1024 + kb0);
        if (t < NKT - 2) { STAGE3_0(t + 2, sslot); }
        __builtin_amdgcn_s_barrier();
        asm volatile("s_waitcnt lgkmcnt(0)" ::: "memory");
        __builtin_amdgcn_s_setprio(1);
        #pragma unroll
        for (int m = 0; m < 4; ++m)
            #pragma unroll
            for (int n = 0; n < 4; ++n)
                acc[m][n] = __builtin_amdgcn_mfma_f32_16x16x32_bf16(av[m], bv[n], acc[m][n], 0, 0, 0);
        __builtin_amdgcn_s_setprio(0);
        __builtin_amdgcn_s_barrier();

        // ---------------- phase 1 (kk = 1)
        #pragma unroll
        for (int m = 0; m < 4; ++m)
            av[m] = *(const bf16x8*)(aS + ar0 + m * 1024 + kb1);
        #pragma unroll
        for (int n = 0; n < 4; ++n)
            bv[n] = *(const bf16x8*)(bS + br0 + n * 1024 + kb1);
        if (t < NKT - 2) { STAGE3_1(t + 2, sslot); }
        if (t < NKT - 2) {
            asm volatile("s_waitcnt vmcnt(6)" ::: "memory");   // t+1 fully landed
        } else if (t == NKT - 2) {
            asm volatile("s_waitcnt vmcnt(0)" ::: "memory");   // drain for t=15
        }
        __builtin_amdgcn_s_barrier();
        asm volatile("s_waitcnt lgkmcnt(0)" ::: "memory");
        __builtin_amdgcn_s_setprio(1);
        #pragma unroll
        for (int m = 0; m < 4; ++m)
            #pragma unroll
            for (int n = 0; n < 4; ++n)
                acc[m][n] = __builtin_amdgcn_mfma_f32_16x16x32_bf16(av[m], bv[n], acc[m][n], 0, 0, 0);
        __builtin_amdgcn_s_setprio(0);
        __builtin_amdgcn_s_barrier();

        slot  = (slot  == 2) ? 0 : slot + 1;
        sslot = (sslot == 2) ? 0 : sslot + 1;
    }

    // ---- epilogue
    const int rq = (lane >> 4) * 4;
    #pragma unroll
    for (int n = 0; n < 4; ++n) {
        const int col = bn + wn * 64 + n * 16 + fr;
        const float bb = bias0[col] + bias1[col];
        #pragma unroll
        for (int m = 0; m < 4; ++m) {
            #pragma unroll
            for (int r = 0; r < 4; ++r) {
                const int row = bm + wm * 64 + m * 16 + rq + r;
                C[(size_t)row * N + col] = f2bf(acc[m][n][r] + bb);
            }
        }
    }
}

// ---------------------------------------------------------------- GEMM2 + gates
// Per 128x64 output tile of h_new: accumulate 3 gate strips (r,z,n) of the
// block-diagonal projection wh = hb @ W_h[k]^T over K=256, then fuse gates.
__global__ __launch_bounds__(256)
void gru_gate_kernel(const unsigned short* __restrict__ Hb,   // [8192][2048] bf16
                     const unsigned short* __restrict__ Wh,   // [8][768][256] bf16
                     const unsigned short* __restrict__ WX,   // [8192][6144] bf16
                     const float* __restrict__ b_hr,          // [6144]
                     const float* __restrict__ Hf,            // [8192][2048] f32
                     float* __restrict__ out) {               // [8192][2048] f32
    constexpr int H = 2048, N3 = 6144, K = 256;
    __shared__ unsigned short As[128 * 32];
    __shared__ unsigned short Bs[192 * 32];

    const int tid  = threadIdx.x;
    const int lane = tid & 63;
    const int w    = tid >> 6;            // wave 0..3 -> rows w*32..w*32+31
    const int bm = blockIdx.y * 128;
    const int colbase = blockIdx.x * 64;  // h-column base (0..2047)
    const int kb  = colbase >> 8;         // diagonal block index
    const int lcb = colbase & 255;        // local column base within block

    const int srow = tid >> 2;
    const int scol = (tid & 3) * 8;

    const unsigned short* ag = Hb + (size_t)(bm + srow) * H + kb * 256 + scol;
    const unsigned short* wb = Wh + (size_t)kb * 768 * 256;

    const int fr = lane & 15;
    const int k0 = (lane >> 4) * 8;

    f32x4 acc[3][2][4] = {};

    for (int kt = 0; kt < K; kt += 32) {
        __syncthreads();
        gload16(ag + kt, &As[srow * 32 + scol]);
        gload16(ag + (size_t)64 * H + kt, &As[(64 + srow) * 32 + scol]);
        #pragma unroll
        for (int i = 0; i < 3; ++i) {
            const unsigned short* src = wb + (size_t)(i * 256 + lcb + srow) * 256 + kt + scol;
            gload16(src, &Bs[(i * 64 + srow) * 32 + scol]);
        }
        asm volatile("s_waitcnt vmcnt(0)" ::: "memory");
        __syncthreads();

        bf16x8 af[2], bv[3][4];
        #pragma unroll
        for (int m = 0; m < 2; ++m)
            af[m] = *(const bf16x8*)&As[(w * 32 + m * 16 + fr) * 32 + k0];
        #pragma unroll
        for (int s = 0; s < 3; ++s)
            #pragma unroll
            for (int n = 0; n < 4; ++n)
                bv[s][n] = *(const bf16x8*)&Bs[(s * 64 + n * 16 + fr) * 32 + k0];
        #pragma unroll
        for (int s = 0; s < 3; ++s)
            #pragma unroll
            for (int m = 0; m < 2; ++m)
                #pragma unroll
                for (int n = 0; n < 4; ++n)
                    acc[s][m][n] = __builtin_amdgcn_mfma_f32_16x16x32_bf16(af[m], bv[s][n], acc[s][m][n], 0, 0, 0);
    }

    const int rbase = (lane >> 4) * 4;
    #pragma unroll
    for (int n = 0; n < 4; ++n) {
        const int lcol = lcb + n * 16 + fr;       // 0..255 within block
        const int hcol = colbase + n * 16 + fr;   // 0..2047
        const float br  = b_hr[kb * 768 + lcol];
        const float bz  = b_hr[kb * 768 + 256 + lcol];
        const float bnn = b_hr[kb * 768 + 512 + lcol];
        #pragma unroll
        for (int m = 0; m < 2; ++m) {
            #pragma unroll
            for (int r = 0; r < 4; ++r) {
                const int row = bm + w * 32 + m * 16 + rbase + r;
                const size_t wxoff = (size_t)row * N3 + hcol;
                const float wxr = bf2f(WX[wxoff]);
                const float wxz = bf2f(WX[wxoff + H]);
                const float wxn = bf2f(WX[wxoff + 2 * H]);
                const float whr = acc[0][m][n][r] + br;
                const float whz = acc[1][m][n][r] + bz;
                const float whn = acc[2][m][n][r] + bnn;
                const float rg = sigmoidf_(wxr + whr);
                const float zg = sigmoidf_(wxz + whz);
                const float ng = tanhf_(wxn + rg * whn);
                const float hv = Hf[(size_t)row * H + hcol];
                out[(size_t)row * H + hcol] = (1.0f - zg) * hv + zg * ng;
            }
        }
    }
}

// ---------------------------------------------------------------- launch
extern "C" void kernel_launch(void* const* d_in, const int* in_sizes, int n_in,
                              void* d_out, int out_size, void* d_ws, size_t ws_size,
                              hipStream_t stream) {
    const float* x        = (const float*)d_in[0];  // [8192][1024]
    const float* h        = (const float*)d_in[1];  // [8192][2048]
    const float* W_ir     = (const float*)d_in[2];  // [6144][1024]
    const float* b_ir_lin = (const float*)d_in[3];  // [6144]
    const float* b_ir     = (const float*)d_in[4];  // [6144]
    const float* W_h      = (const float*)d_in[5];  // [8][768][256]
    const float* b_hr     = (const float*)d_in[6];  // [6144]
    float* out = (float*)d_out;                     // [8192][2048]

    char* ws = (char*)d_ws;
    unsigned short* xb   = (unsigned short*)(ws);                    // 16,777,216 B
    unsigned short* wirb = (unsigned short*)(ws + 16777216);         // 12,582,912 B
    unsigned short* hb   = (unsigned short*)(ws + 29360128);         // 33,554,432 B
    unsigned short* whb  = (unsigned short*)(ws + 62914560);         //  3,145,728 B
    unsigned short* wx   = (unsigned short*)(ws + 66060288);         // 100,663,296 B (end ~159 MiB)

    cast_f32_to_bf16<<<8192,  256, 0, stream>>>(x,    xb,   2097152);
    cast_f32_to_bf16<<<6144,  256, 0, stream>>>(W_ir, wirb, 1572864);
    cast_f32_to_bf16<<<16384, 256, 0, stream>>>(h,    hb,   4194304);
    cast_f32_to_bf16<<<1536,  256, 0, stream>>>(W_h,  whb,  393216);

    gemm_wx_8phase<<<1536, 512, 0, stream>>>(xb, wirb, b_ir_lin, b_ir, wx);

    dim3 g2(32, 64);   // H/64 x M/128
    gru_gate_kernel<<<g2, 256, 0, stream>>>(hb, whb, wx, b_hr, h, out);
}

// Round 3
// 269.819 us; speedup vs baseline: 1.1060x; 1.0732x over previous
//
#include <hip/hip_runtime.h>
#include <cstdint>
#include <cstddef>

// Block-diagonal GRU on MI355X (gfx950), bf16 MFMA path.
// B=8192, IN=1024, H=2048, NB=8, BS=256, 3H=6144.

typedef __attribute__((ext_vector_type(8))) short bf16x8;
typedef __attribute__((ext_vector_type(4))) float f32x4;

__device__ __forceinline__ unsigned short f2bf(float f) {
    uint32_t u = __float_as_uint(f);
    u += 0x7FFFu + ((u >> 16) & 1u);   // round-to-nearest-even
    return (unsigned short)(u >> 16);
}
__device__ __forceinline__ float bf2f(unsigned short b) {
    return __uint_as_float(((uint32_t)b) << 16);
}

__device__ __forceinline__ void gload16(const void* g, void* l) {
    __builtin_amdgcn_global_load_lds(
        (const __attribute__((address_space(1))) void*)g,
        (__attribute__((address_space(3))) void*)l,
        16, 0, 0);
}

__device__ __forceinline__ float sigmoidf_(float x) {
    return 1.0f / (1.0f + __expf(-x));
}
__device__ __forceinline__ float tanhf_(float x) {
    float e = __expf(-2.0f * fabsf(x));
    float t = (1.0f - e) / (1.0f + e);
    return copysignf(t, x);
}

// ---------------------------------------------------------------- casts
__global__ __launch_bounds__(256)
void cast_f32_to_bf16(const float* __restrict__ s, unsigned short* __restrict__ d, int n4) {
    int i = blockIdx.x * 256 + threadIdx.x;
    if (i >= n4) return;
    const float4 v = *reinterpret_cast<const float4*>(s + (size_t)i * 4);
    ushort4 o;
    o.x = f2bf(v.x); o.y = f2bf(v.y); o.z = f2bf(v.z); o.w = f2bf(v.w);
    *reinterpret_cast<ushort4*>(d + (size_t)i * 4) = o;
}

// ---------------------------------------------------------------- GEMM1
// wx = x @ W_ir^T + b_ir_lin + b_ir  (bf16 out)
// BM=BN=256, BK=64, 8 waves (2M x 4N), wave-tile 128x64, acc[8][4].
// LDS: 2 slots x (A 256x64 + B 256x64) bf16 = 128 KiB, XOR-swizzled rows.
// Per K-tile per thread: 8 gload_lds (B steps 0-3, A steps 0,2,1,3).
// 4 phases x 16 MFMA; staging of tile t+1 interleaved; waits vmcnt(4)/(6),
// last tile peeled with vmcnt(2)/(0).
// A step s covers tile rows [s*64, s*64+64); same for B.

__global__ __launch_bounds__(512, 2)
void gemm_wx_256(const unsigned short* __restrict__ A,
                 const unsigned short* __restrict__ Bt,
                 const float* __restrict__ bias0,
                 const float* __restrict__ bias1,
                 unsigned short* __restrict__ C) {
    constexpr int N = 6144, K = 1024;
    constexpr int NKT = 16;   // K / 64
    __shared__ unsigned short lds[4 * 16384];     // 128 KiB
    unsigned short* const As = lds;               // 2 slots x 16384 elem
    unsigned short* const Bs = lds + 2 * 16384;

    const int tid  = threadIdx.x;
    const int lane = tid & 63;
    const int w    = tid >> 6;
    const int wm   = w >> 2;      // 0..1  (row half, 128 rows)
    const int wn   = w & 3;       // 0..3  (col quarter, 64 cols)

    // XCD swizzle: 768 blocks = 8 XCD x (3 bn-tiles x 32 bm-tiles), bm fastest.
    // Each XCD owns 3 exclusive bn columns -> B-panel L2-resident.
    const int bid = blockIdx.x;
    const int xcd = bid & 7;
    const int idx = bid >> 3;          // 0..95
    const int bn  = (xcd * 3 + (idx >> 5)) * 256;
    const int bm  = (idx & 31) * 256;

    // ---- staging source (inverse-swizzled global, linear LDS dest)
    const int srow  = tid >> 3;                       // row within 64-row step
    const int chunk = (tid & 7) ^ (srow & 7);         // 16B chunk, XOR-inverse
    const int scol  = chunk * 8;                      // element col in 64-wide row
    const int doff  = tid * 8;                        // element offset in 8KB step
    const unsigned short* sA[4];
    const unsigned short* sB[4];
    #pragma unroll
    for (int s = 0; s < 4; ++s) {
        sA[s] = A  + (size_t)(bm + s * 64 + srow) * K + scol;
        sB[s] = Bt + (size_t)(bn + s * 64 + srow) * K + scol;
    }

#define ISSUE_A(st, kt, ds) gload16(sA[st] + (size_t)(kt) * 64, As + (ds) * 16384 + (st) * 4096 + doff)
#define ISSUE_B(st, kt, ds) gload16(sB[st] + (size_t)(kt) * 64, Bs + (ds) * 16384 + (st) * 4096 + doff)

    // ---- fragment read offsets (swizzled reads, rows are 128 B)
    const int fr  = lane & 15;
    const int k0e = (lane >> 4) * 8;
    const int mfr = (fr & 7) << 4;
    const int kb0 = ((k0e * 2) ^ mfr) >> 1;        // kk=0 element offset
    const int kb1 = (((k0e * 2) + 64) ^ mfr) >> 1; // kk=1

#define LDA(m, kb) (*(const bf16x8*)(aS + (wm * 128 + (m) * 16 + fr) * 64 + (kb)))
#define LDB(n, kb) (*(const bf16x8*)(bS + (wn * 64  + (n) * 16 + fr) * 64 + (kb)))
#define MFMA16(mb) do {                                                        \
    asm volatile("s_waitcnt lgkmcnt(0)" ::: "memory");                         \
    __builtin_amdgcn_sched_barrier(0);                                         \
    __builtin_amdgcn_s_setprio(1);                                             \
    _Pragma("unroll")                                                          \
    for (int m = 0; m < 4; ++m)                                                \
        _Pragma("unroll")                                                      \
        for (int n = 0; n < 4; ++n)                                            \
            acc[(mb) + m][n] =                                                 \
                __builtin_amdgcn_mfma_f32_16x16x32_bf16(av[m], bv[n],          \
                                                        acc[(mb) + m][n], 0, 0, 0); \
    __builtin_amdgcn_s_setprio(0);                                             \
} while (0)

    f32x4 acc[8][4] = {};
    bf16x8 av[4], bv[4];

    // ---- prologue: tile 0, order B0,B1,B2,B3,A0,A2,A1,A3
    ISSUE_B(0, 0, 0); ISSUE_B(1, 0, 0); ISSUE_B(2, 0, 0); ISSUE_B(3, 0, 0);
    ISSUE_A(0, 0, 0); ISSUE_A(2, 0, 0); ISSUE_A(1, 0, 0); ISSUE_A(3, 0, 0);

    #pragma unroll 1
    for (int t = 0; t < NKT - 1; ++t) {
        const int slot = t & 1, nxt = slot ^ 1;
        const unsigned short* aS = As + slot * 16384;
        const unsigned short* bS = Bs + slot * 16384;

        // ---- P0: kk0, m0-3
        ISSUE_B(0, t + 1, nxt); ISSUE_B(1, t + 1, nxt);
        asm volatile("s_waitcnt vmcnt(4)" ::: "memory");
        __builtin_amdgcn_s_barrier();
        #pragma unroll
        for (int m = 0; m < 4; ++m) av[m] = LDA(m, kb0);
        #pragma unroll
        for (int n = 0; n < 4; ++n) bv[n] = LDB(n, kb0);
        MFMA16(0);

        // ---- P1: kk0, m4-7 (bv reused)
        ISSUE_B(2, t + 1, nxt); ISSUE_B(3, t + 1, nxt);
        ISSUE_A(0, t + 1, nxt); ISSUE_A(2, t + 1, nxt);
        asm volatile("s_waitcnt vmcnt(6)" ::: "memory");
        __builtin_amdgcn_s_barrier();
        #pragma unroll
        for (int m = 0; m < 4; ++m) av[m] = LDA(4 + m, kb0);
        MFMA16(4);

        // ---- P2: kk1, m0-3
        ISSUE_A(1, t + 1, nxt); ISSUE_A(3, t + 1, nxt);
        #pragma unroll
        for (int n = 0; n < 4; ++n) bv[n] = LDB(n, kb1);
        #pragma unroll
        for (int m = 0; m < 4; ++m) av[m] = LDA(m, kb1);
        MFMA16(0);

        // ---- P3: kk1, m4-7 (bv reused)
        #pragma unroll
        for (int m = 0; m < 4; ++m) av[m] = LDA(4 + m, kb1);
        MFMA16(4);
        __builtin_amdgcn_s_barrier();   // slot protection before next tile's issues
    }

    // ---- peeled last tile (t = NKT-1): no issues, drain waits
    {
        const int slot = (NKT - 1) & 1;
        const unsigned short* aS = As + slot * 16384;
        const unsigned short* bS = Bs + slot * 16384;

        asm volatile("s_waitcnt vmcnt(2)" ::: "memory");
        __builtin_amdgcn_s_barrier();
        #pragma unroll
        for (int m = 0; m < 4; ++m) av[m] = LDA(m, kb0);
        #pragma unroll
        for (int n = 0; n < 4; ++n) bv[n] = LDB(n, kb0);
        MFMA16(0);

        asm volatile("s_waitcnt vmcnt(0)" ::: "memory");
        __builtin_amdgcn_s_barrier();
        #pragma unroll
        for (int m = 0; m < 4; ++m) av[m] = LDA(4 + m, kb0);
        MFMA16(4);

        #pragma unroll
        for (int n = 0; n < 4; ++n) bv[n] = LDB(n, kb1);
        #pragma unroll
        for (int m = 0; m < 4; ++m) av[m] = LDA(m, kb1);
        MFMA16(0);

        #pragma unroll
        for (int m = 0; m < 4; ++m) av[m] = LDA(4 + m, kb1);
        MFMA16(4);
    }

    // ---- epilogue
    const int rq = (lane >> 4) * 4;
    #pragma unroll
    for (int n = 0; n < 4; ++n) {
        const int col = bn + wn * 64 + n * 16 + fr;
        const float bb = bias0[col] + bias1[col];
        #pragma unroll
        for (int mi = 0; mi < 8; ++mi) {
            #pragma unroll
            for (int r = 0; r < 4; ++r) {
                const int row = bm + wm * 128 + mi * 16 + rq + r;
                C[(size_t)row * N + col] = f2bf(acc[mi][n][r] + bb);
            }
        }
    }
#undef ISSUE_A
#undef ISSUE_B
#undef LDA
#undef LDB
#undef MFMA16
}

// ---------------------------------------------------------------- GEMM2 + gates
__global__ __launch_bounds__(256)
void gru_gate_kernel(const unsigned short* __restrict__ Hb,   // [8192][2048] bf16
                     const unsigned short* __restrict__ Wh,   // [8][768][256] bf16
                     const unsigned short* __restrict__ WX,   // [8192][6144] bf16
                     const float* __restrict__ b_hr,          // [6144]
                     const float* __restrict__ Hf,            // [8192][2048] f32
                     float* __restrict__ out) {               // [8192][2048] f32
    constexpr int H = 2048, N3 = 6144, K = 256;
    __shared__ unsigned short As[128 * 32];
    __shared__ unsigned short Bs[192 * 32];

    const int tid  = threadIdx.x;
    const int lane = tid & 63;
    const int w    = tid >> 6;
    const int bm = blockIdx.y * 128;
    const int colbase = blockIdx.x * 64;
    const int kb  = colbase >> 8;
    const int lcb = colbase & 255;

    const int srow = tid >> 2;
    const int scol = (tid & 3) * 8;

    const unsigned short* ag = Hb + (size_t)(bm + srow) * H + kb * 256 + scol;
    const unsigned short* wb = Wh + (size_t)kb * 768 * 256;

    const int fr = lane & 15;
    const int k0 = (lane >> 4) * 8;

    f32x4 acc[3][2][4] = {};

    for (int kt = 0; kt < K; kt += 32) {
        __syncthreads();
        gload16(ag + kt, &As[srow * 32 + scol]);
        gload16(ag + (size_t)64 * H + kt, &As[(64 + srow) * 32 + scol]);
        #pragma unroll
        for (int i = 0; i < 3; ++i) {
            const unsigned short* src = wb + (size_t)(i * 256 + lcb + srow) * 256 + kt + scol;
            gload16(src, &Bs[(i * 64 + srow) * 32 + scol]);
        }
        asm volatile("s_waitcnt vmcnt(0)" ::: "memory");
        __syncthreads();

        bf16x8 af[2], bv[3][4];
        #pragma unroll
        for (int m = 0; m < 2; ++m)
            af[m] = *(const bf16x8*)&As[(w * 32 + m * 16 + fr) * 32 + k0];
        #pragma unroll
        for (int s = 0; s < 3; ++s)
            #pragma unroll
            for (int n = 0; n < 4; ++n)
                bv[s][n] = *(const bf16x8*)&Bs[(s * 64 + n * 16 + fr) * 32 + k0];
        #pragma unroll
        for (int s = 0; s < 3; ++s)
            #pragma unroll
            for (int m = 0; m < 2; ++m)
                #pragma unroll
                for (int n = 0; n < 4; ++n)
                    acc[s][m][n] = __builtin_amdgcn_mfma_f32_16x16x32_bf16(af[m], bv[s][n], acc[s][m][n], 0, 0, 0);
    }

    const int rbase = (lane >> 4) * 4;
    #pragma unroll
    for (int n = 0; n < 4; ++n) {
        const int lcol = lcb + n * 16 + fr;
        const int hcol = colbase + n * 16 + fr;
        const float br  = b_hr[kb * 768 + lcol];
        const float bz  = b_hr[kb * 768 + 256 + lcol];
        const float bnn = b_hr[kb * 768 + 512 + lcol];
        #pragma unroll
        for (int m = 0; m < 2; ++m) {
            #pragma unroll
            for (int r = 0; r < 4; ++r) {
                const int row = bm + w * 32 + m * 16 + rbase + r;
                const size_t wxoff = (size_t)row * N3 + hcol;
                const float wxr = bf2f(WX[wxoff]);
                const float wxz = bf2f(WX[wxoff + H]);
                const float wxn = bf2f(WX[wxoff + 2 * H]);
                const float whr = acc[0][m][n][r] + br;
                const float whz = acc[1][m][n][r] + bz;
                const float whn = acc[2][m][n][r] + bnn;
                const float rg = sigmoidf_(wxr + whr);
                const float zg = sigmoidf_(wxz + whz);
                const float ng = tanhf_(wxn + rg * whn);
                const float hv = Hf[(size_t)row * H + hcol];
                out[(size_t)row * H + hcol] = (1.0f - zg) * hv + zg * ng;
            }
        }
    }
}

// ---------------------------------------------------------------- launch
extern "C" void kernel_launch(void* const* d_in, const int* in_sizes, int n_in,
                              void* d_out, int out_size, void* d_ws, size_t ws_size,
                              hipStream_t stream) {
    const float* x        = (const float*)d_in[0];
    const float* h        = (const float*)d_in[1];
    const float* W_ir     = (const float*)d_in[2];
    const float* b_ir_lin = (const float*)d_in[3];
    const float* b_ir     = (const float*)d_in[4];
    const float* W_h      = (const float*)d_in[5];
    const float* b_hr     = (const float*)d_in[6];
    float* out = (float*)d_out;

    char* ws = (char*)d_ws;
    unsigned short* xb   = (unsigned short*)(ws);
    unsigned short* wirb = (unsigned short*)(ws + 16777216);
    unsigned short* hb   = (unsigned short*)(ws + 29360128);
    unsigned short* whb  = (unsigned short*)(ws + 62914560);
    unsigned short* wx   = (unsigned short*)(ws + 66060288);

    cast_f32_to_bf16<<<8192,  256, 0, stream>>>(x,    xb,   2097152);
    cast_f32_to_bf16<<<6144,  256, 0, stream>>>(W_ir, wirb, 1572864);
    cast_f32_to_bf16<<<16384, 256, 0, stream>>>(h,    hb,   4194304);
    cast_f32_to_bf16<<<1536,  256, 0, stream>>>(W_h,  whb,  393216);

    gemm_wx_256<<<768, 512, 0, stream>>>(xb, wirb, b_ir_lin, b_ir, wx);

    dim3 g2(32, 64);
    gru_gate_kernel<<<g2, 256, 0, stream>>>(hb, whb, wx, b_hr, h, out);
}

// Round 4
// 182.117 us; speedup vs baseline: 1.6387x; 1.4816x over previous
//
#include <hip/hip_runtime.h>
#include <cstdint>
#include <cstddef>

// Block-diagonal GRU on MI355X (gfx950), fully fused bf16 MFMA path.
// B=8192, IN=1024, H=2048, NB=8, BS=256, 3H=6144.
// One GEMM kernel computes wx (K=1024) AND wh (K=256, block-diagonal) for a
// 256x64 h-column tile, then applies the GRU gates in the epilogue.

typedef __attribute__((ext_vector_type(8))) short bf16x8;
typedef __attribute__((ext_vector_type(4))) float f32x4;

__device__ __forceinline__ unsigned short f2bf(float f) {
    uint32_t u = __float_as_uint(f);
    u += 0x7FFFu + ((u >> 16) & 1u);   // round-to-nearest-even
    return (unsigned short)(u >> 16);
}

__device__ __forceinline__ void gload16(const void* g, void* l) {
    __builtin_amdgcn_global_load_lds(
        (const __attribute__((address_space(1))) void*)g,
        (__attribute__((address_space(3))) void*)l,
        16, 0, 0);
}

__device__ __forceinline__ float sigmoidf_(float x) {
    return 1.0f / (1.0f + __expf(-x));
}
__device__ __forceinline__ float tanhf_(float x) {
    float e = __expf(-2.0f * fabsf(x));
    float t = (1.0f - e) / (1.0f + e);
    return copysignf(t, x);
}

// ---------------------------------------------------------------- casts
__global__ __launch_bounds__(256)
void cast_f32_to_bf16(const float* __restrict__ s, unsigned short* __restrict__ d, int n4) {
    int i = blockIdx.x * 256 + threadIdx.x;
    if (i >= n4) return;
    const float4 v = *reinterpret_cast<const float4*>(s + (size_t)i * 4);
    ushort4 o;
    o.x = f2bf(v.x); o.y = f2bf(v.y); o.z = f2bf(v.z); o.w = f2bf(v.w);
    *reinterpret_cast<ushort4*>(d + (size_t)i * 4) = o;
}

// ---------------------------------------------------------------- fused GRU
// Output tile: 256 rows x 64 h-cols. 8 waves (2M x 4N): wave = 128 rows x 16
// cols x 3 strips. A tile 256x64 (4 steps), B tile 192x64 (3 strips).
// 20 K-tiles: 0..15 phase1 (x @ W_ir^T), 16..19 phase2 (hb @ W_h[kb]^T).
// acc groups: 0=r(sum), 1=z(sum), 2=wxn, 3=whn.  NT = 2 (phase1) / 3 (phase2).
// LDS: 2 slots x (A 32KB + B 24KB) = 112 KiB, XOR-swizzled (T2).
// Issues per K-tile: B0,B1,B2 | A0,A2 | A1,A3 ; waits vmcnt(5)/(5), peel (2)/(0).

#define MFMA12(mb, NT) do {                                                    \
    asm volatile("s_waitcnt lgkmcnt(0)" ::: "memory");                         \
    __builtin_amdgcn_sched_barrier(0);                                         \
    __builtin_amdgcn_s_setprio(1);                                             \
    _Pragma("unroll")                                                          \
    for (int m_ = 0; m_ < 4; ++m_) {                                           \
        acc[0][(mb) + m_] = __builtin_amdgcn_mfma_f32_16x16x32_bf16(           \
            av[m_], bv[0], acc[0][(mb) + m_], 0, 0, 0);                        \
        acc[1][(mb) + m_] = __builtin_amdgcn_mfma_f32_16x16x32_bf16(           \
            av[m_], bv[1], acc[1][(mb) + m_], 0, 0, 0);                        \
        acc[NT][(mb) + m_] = __builtin_amdgcn_mfma_f32_16x16x32_bf16(          \
            av[m_], bv[2], acc[NT][(mb) + m_], 0, 0, 0);                       \
    }                                                                          \
    __builtin_amdgcn_s_setprio(0);                                             \
} while (0)

#define LDA(m, kb_) (*(const bf16x8*)(aS + (wm * 128 + (m) * 16 + fr) * 64 + (kb_)))
#define LDB(s, kb_) (*(const bf16x8*)(bS + ((s) * 64 + wn * 16 + fr) * 64 + (kb_)))

#define IB1(kt, ds) do {                                                       \
    gload16(b1[0] + (size_t)(kt) * 64, Bs + (ds) * 12288 + doff);              \
    gload16(b1[1] + (size_t)(kt) * 64, Bs + (ds) * 12288 + 4096 + doff);       \
    gload16(b1[2] + (size_t)(kt) * 64, Bs + (ds) * 12288 + 8192 + doff); } while (0)
#define IA1a(kt, ds) do {                                                      \
    gload16(a1[0] + (size_t)(kt) * 64, As + (ds) * 16384 + doff);              \
    gload16(a1[2] + (size_t)(kt) * 64, As + (ds) * 16384 + 8192 + doff); } while (0)
#define IA1b(kt, ds) do {                                                      \
    gload16(a1[1] + (size_t)(kt) * 64, As + (ds) * 16384 + 4096 + doff);       \
    gload16(a1[3] + (size_t)(kt) * 64, As + (ds) * 16384 + 12288 + doff); } while (0)
#define IB2(k2, ds) do {                                                       \
    gload16(b2[0] + (size_t)(k2) * 64, Bs + (ds) * 12288 + doff);              \
    gload16(b2[1] + (size_t)(k2) * 64, Bs + (ds) * 12288 + 4096 + doff);       \
    gload16(b2[2] + (size_t)(k2) * 64, Bs + (ds) * 12288 + 8192 + doff); } while (0)
#define IA2a(k2, ds) do {                                                      \
    gload16(a2[0] + (size_t)(k2) * 64, As + (ds) * 16384 + doff);              \
    gload16(a2[2] + (size_t)(k2) * 64, As + (ds) * 16384 + 8192 + doff); } while (0)
#define IA2b(k2, ds) do {                                                      \
    gload16(a2[1] + (size_t)(k2) * 64, As + (ds) * 16384 + 4096 + doff);       \
    gload16(a2[3] + (size_t)(k2) * 64, As + (ds) * 16384 + 12288 + doff); } while (0)

// One K-tile: P0 {issue I0, wait W0, bar, reads kb0 m0-3 + B, 12 MFMA}
//             P1 {issue I1, wait W1, bar, reads kb0 m4-7, 12 MFMA}
//             P2 {issue I2, reads kb1 m0-3 + B, 12 MFMA}
//             P3 {reads kb1 m4-7, 12 MFMA, bar (slot protection)}
#define KSTEP(slot_, I0, W0, I1, W1, I2, NT) do {                              \
    const unsigned short* aS = As + (slot_) * 16384;                           \
    const unsigned short* bS = Bs + (slot_) * 12288;                           \
    I0;                                                                        \
    asm volatile("s_waitcnt vmcnt(" W0 ")" ::: "memory");                      \
    __builtin_amdgcn_s_barrier();                                              \
    _Pragma("unroll") for (int m_ = 0; m_ < 4; ++m_) av[m_] = LDA(m_, kb0);    \
    _Pragma("unroll") for (int s_ = 0; s_ < 3; ++s_) bv[s_] = LDB(s_, kb0);    \
    MFMA12(0, NT);                                                             \
    I1;                                                                        \
    asm volatile("s_waitcnt vmcnt(" W1 ")" ::: "memory");                      \
    __builtin_amdgcn_s_barrier();                                              \
    _Pragma("unroll") for (int m_ = 0; m_ < 4; ++m_) av[m_] = LDA(4 + m_, kb0);\
    MFMA12(4, NT);                                                             \
    I2;                                                                        \
    _Pragma("unroll") for (int m_ = 0; m_ < 4; ++m_) av[m_] = LDA(m_, kb1);    \
    _Pragma("unroll") for (int s_ = 0; s_ < 3; ++s_) bv[s_] = LDB(s_, kb1);    \
    MFMA12(0, NT);                                                             \
    _Pragma("unroll") for (int m_ = 0; m_ < 4; ++m_) av[m_] = LDA(4 + m_, kb1);\
    MFMA12(4, NT);                                                             \
    __builtin_amdgcn_s_barrier();                                              \
} while (0)

__global__ __launch_bounds__(512, 2)
void gru_fused(const unsigned short* __restrict__ Xb,    // [8192][1024] bf16
               const unsigned short* __restrict__ Wirb,  // [6144][1024] bf16
               const unsigned short* __restrict__ Hbb,   // [8192][2048] bf16
               const unsigned short* __restrict__ Whb,   // [8][768][256] bf16
               const float* __restrict__ b_ir_lin,       // [6144]
               const float* __restrict__ b_ir,           // [6144]
               const float* __restrict__ b_hr,           // [6144]
               const float* __restrict__ Hf,             // [8192][2048] f32
               float* __restrict__ out) {                // [8192][2048] f32
    constexpr int K1 = 1024, H = 2048;
    __shared__ unsigned short lds[2 * 16384 + 2 * 12288];   // 112 KiB
    unsigned short* const As = lds;
    unsigned short* const Bs = lds + 2 * 16384;

    const int tid  = threadIdx.x;
    const int lane = tid & 63;
    const int w    = tid >> 6;
    const int wm   = w >> 2;     // 0..1  (128-row half)
    const int wn   = w & 3;      // 0..3  (16-col quarter of the 64 h-cols)

    // Grid: 1024 = 8 kb (XCD-exclusive) x 32 bm x 4 hsub (hsub innermost
    // within an XCD -> A-panel L2 reuse; W_h[kb] + W_ir strips L2-resident).
    const int bid  = blockIdx.x;
    const int kb   = bid & 7;
    const int idx  = bid >> 3;          // 0..127
    const int bm   = (idx >> 2) * 256;
    const int hsub = idx & 3;
    const int hcb  = kb * 256 + hsub * 64;   // h-column base

    // ---- staging sources (inverse-swizzled global, linear LDS dest)
    const int srow  = tid >> 3;                 // 0..63 within a 64-row step
    const int chunk = (tid & 7) ^ (srow & 7);   // T2 XOR involution
    const int scol  = chunk * 8;
    const int doff  = tid * 8;
    const unsigned short* a1[4];
    const unsigned short* a2[4];
    #pragma unroll
    for (int s = 0; s < 4; ++s) {
        a1[s] = Xb  + (size_t)(bm + s * 64 + srow) * K1 + scol;
        a2[s] = Hbb + (size_t)(bm + s * 64 + srow) * H + kb * 256 + scol;
    }
    const unsigned short* b1[3];
    const unsigned short* b2[3];
    #pragma unroll
    for (int s = 0; s < 3; ++s) {
        b1[s] = Wirb + (size_t)(s * 2048 + hcb + srow) * K1 + scol;
        b2[s] = Whb + (size_t)kb * 196608 + (size_t)(s * 256 + hsub * 64 + srow) * 256 + scol;
    }

    // ---- fragment read offsets (swizzled reads, rows are 128 B)
    const int fr  = lane & 15;
    const int k0e = (lane >> 4) * 8;
    const int mfr = (fr & 7) << 4;
    const int kb0 = ((k0e * 2) ^ mfr) >> 1;
    const int kb1 = (((k0e * 2) + 64) ^ mfr) >> 1;

    f32x4 acc[4][8] = {};   // [r, z, wxn, whn][m-frag]
    bf16x8 av[4], bv[3];

    // ---- prologue: tile 0 (phase1): B0,B1,B2,A0,A2,A1,A3
    IB1(0, 0); IA1a(0, 0); IA1b(0, 0);

    // ---- phase1 main: tiles 0..14 (issue t+1, phase1)
    #pragma unroll 1
    for (int t = 0; t < 15; ++t) {
        const int sl = t & 1, nx = sl ^ 1;
        KSTEP(sl, IB1(t + 1, nx), "5", IA1a(t + 1, nx), "5", IA1b(t + 1, nx), 2);
    }
    // ---- bridge: compute tile 15 (phase1), issue tile 16 (phase2, k2=0)
    KSTEP(1, IB2(0, 0), "5", IA2a(0, 0), "5", IA2b(0, 0), 2);
    // ---- phase2: tiles 16..18 (issue t+1, phase2)
    #pragma unroll 1
    for (int t = 16; t < 19; ++t) {
        const int sl = t & 1, nx = sl ^ 1;
        KSTEP(sl, IB2(t - 15, nx), "5", IA2a(t - 15, nx), "5", IA2b(t - 15, nx), 3);
    }
    // ---- peel: tile 19, drain
    KSTEP(1, ((void)0), "2", ((void)0), "0", ((void)0), 3);

    // ---- gate epilogue
    const int rq   = (lane >> 4) * 4;
    const int hcol = hcb + wn * 16 + fr;     // 0..2047
    const int lcol = hcol & 255;             // within diagonal block
    const float bir0 = b_ir_lin[hcol]        + b_ir[hcol];
    const float bir1 = b_ir_lin[2048 + hcol] + b_ir[2048 + hcol];
    const float bir2 = b_ir_lin[4096 + hcol] + b_ir[4096 + hcol];
    const float bhr0 = b_hr[kb * 768 + lcol];
    const float bhr1 = b_hr[kb * 768 + 256 + lcol];
    const float bhr2 = b_hr[kb * 768 + 512 + lcol];
    #pragma unroll
    for (int mi = 0; mi < 8; ++mi) {
        #pragma unroll
        for (int r = 0; r < 4; ++r) {
            const int row = bm + wm * 128 + mi * 16 + rq + r;
            const float pr = acc[0][mi][r] + bir0 + bhr0;
            const float pz = acc[1][mi][r] + bir1 + bhr1;
            const float xn = acc[2][mi][r] + bir2;
            const float hn = acc[3][mi][r] + bhr2;
            const float rg = sigmoidf_(pr);
            const float zg = sigmoidf_(pz);
            const float ng = tanhf_(xn + rg * hn);
            const float hv = Hf[(size_t)row * H + hcol];
            out[(size_t)row * H + hcol] = (1.0f - zg) * hv + zg * ng;
        }
    }
}

// ---------------------------------------------------------------- launch
extern "C" void kernel_launch(void* const* d_in, const int* in_sizes, int n_in,
                              void* d_out, int out_size, void* d_ws, size_t ws_size,
                              hipStream_t stream) {
    const float* x        = (const float*)d_in[0];
    const float* h        = (const float*)d_in[1];
    const float* W_ir     = (const float*)d_in[2];
    const float* b_ir_lin = (const float*)d_in[3];
    const float* b_ir     = (const float*)d_in[4];
    const float* W_h      = (const float*)d_in[5];
    const float* b_hr     = (const float*)d_in[6];
    float* out = (float*)d_out;

    char* ws = (char*)d_ws;
    unsigned short* xb   = (unsigned short*)(ws);               // 16 MiB
    unsigned short* wirb = (unsigned short*)(ws + 16777216);    // 12 MiB
    unsigned short* hb   = (unsigned short*)(ws + 29360128);    // 32 MiB
    unsigned short* whb  = (unsigned short*)(ws + 62914560);    //  3 MiB

    cast_f32_to_bf16<<<8192,  256, 0, stream>>>(x,    xb,   2097152);
    cast_f32_to_bf16<<<6144,  256, 0, stream>>>(W_ir, wirb, 1572864);
    cast_f32_to_bf16<<<16384, 256, 0, stream>>>(h,    hb,   4194304);
    cast_f32_to_bf16<<<1536,  256, 0, stream>>>(W_h,  whb,  393216);

    gru_fused<<<1024, 512, 0, stream>>>(xb, wirb, hb, whb,
                                        b_ir_lin, b_ir, b_hr, h, out);
}

// Round 5
// 177.559 us; speedup vs baseline: 1.6807x; 1.0257x over previous
//
#include <hip/hip_runtime.h>
#include <cstdint>
#include <cstddef>

// Block-diagonal GRU on MI355X (gfx950), fully fused bf16 MFMA path.
// B=8192, IN=1024, H=2048, NB=8, BS=256, 3H=6144.
// One kernel computes wx (K=1024) AND wh (K=256, block-diagonal) for a
// 128x64 h-column tile, then applies the GRU gates in the epilogue.
// Geometry: 256 thr (4 waves 2Mx2N), BM=128, BK=64, LDS 80 KiB -> 2 blocks/CU.

typedef __attribute__((ext_vector_type(8))) short bf16x8;
typedef __attribute__((ext_vector_type(4))) float f32x4;

__device__ __forceinline__ unsigned short f2bf(float f) {
    uint32_t u = __float_as_uint(f);
    u += 0x7FFFu + ((u >> 16) & 1u);   // round-to-nearest-even
    return (unsigned short)(u >> 16);
}

__device__ __forceinline__ void gload16(const void* g, void* l) {
    __builtin_amdgcn_global_load_lds(
        (const __attribute__((address_space(1))) void*)g,
        (__attribute__((address_space(3))) void*)l,
        16, 0, 0);
}

__device__ __forceinline__ float sigmoidf_(float x) {
    return 1.0f / (1.0f + __expf(-x));
}
__device__ __forceinline__ float tanhf_(float x) {
    float e = __expf(-2.0f * fabsf(x));
    float t = (1.0f - e) / (1.0f + e);
    return copysignf(t, x);
}

// ---------------------------------------------------------------- casts
__global__ __launch_bounds__(256)
void cast_f32_to_bf16(const float* __restrict__ s, unsigned short* __restrict__ d, int n4) {
    int i = blockIdx.x * 256 + threadIdx.x;
    if (i >= n4) return;
    const float4 v = *reinterpret_cast<const float4*>(s + (size_t)i * 4);
    ushort4 o;
    o.x = f2bf(v.x); o.y = f2bf(v.y); o.z = f2bf(v.z); o.w = f2bf(v.w);
    *reinterpret_cast<ushort4*>(d + (size_t)i * 4) = o;
}

// ---------------------------------------------------------------- fused GRU
// acc groups: 0=r(sum of both GEMMs), 1=z(sum), 2=wxn, 3=whn.
// NT = 2 during phase1 (x @ W_ir^T), 3 during phase2 (hb @ W_h[kb]^T).
// A tile 128x64 (4 chunks of 32 rows), B tile 192x64 (6 chunks).
// Issues/thread/K-tile: 10 = [B0..B3] + [B4,B5,A0,A1] + [A2,A3].
// One counted wait vmcnt(4) per K-tile; peel waits vmcnt(0).
// LDS rows are 128 B, T2 XOR-swizzle byte^=(row&7)<<4 via inverse-swizzled
// global source (linear gload_lds dest) + swizzled ds_read (G21).

#define MFMA12(n_, NT) do {                                                    \
    asm volatile("s_waitcnt lgkmcnt(0)" ::: "memory");                         \
    __builtin_amdgcn_sched_barrier(0);                                         \
    __builtin_amdgcn_s_setprio(1);                                             \
    _Pragma("unroll")                                                          \
    for (int m_ = 0; m_ < 4; ++m_) {                                           \
        acc[0][m_][n_] = __builtin_amdgcn_mfma_f32_16x16x32_bf16(              \
            av[m_], bv[0], acc[0][m_][n_], 0, 0, 0);                           \
        acc[1][m_][n_] = __builtin_amdgcn_mfma_f32_16x16x32_bf16(              \
            av[m_], bv[1], acc[1][m_][n_], 0, 0, 0);                           \
        acc[NT][m_][n_] = __builtin_amdgcn_mfma_f32_16x16x32_bf16(             \
            av[m_], bv[2], acc[NT][m_][n_], 0, 0, 0);                          \
    }                                                                          \
    __builtin_amdgcn_s_setprio(0);                                             \
} while (0)

#define LDA(m, kb_) (*(const bf16x8*)(aS + (wm * 64 + (m) * 16 + fr) * 64 + (kb_)))
#define LDB(s, n_, kb_) (*(const bf16x8*)(bS + ((s) * 64 + wn * 32 + (n_) * 16 + fr) * 64 + (kb_)))

// phase1 issue groups (kt in units of 64 elements along K=1024)
#define I0_1(kt, ds) do {                                                      \
    gload16(b1[0] + (size_t)(kt) * 64, Bs + (ds) * 12288 + 0 * 2048 + doff);   \
    gload16(b1[1] + (size_t)(kt) * 64, Bs + (ds) * 12288 + 1 * 2048 + doff);   \
    gload16(b1[2] + (size_t)(kt) * 64, Bs + (ds) * 12288 + 2 * 2048 + doff);   \
    gload16(b1[3] + (size_t)(kt) * 64, Bs + (ds) * 12288 + 3 * 2048 + doff); } while (0)
#define I1_1(kt, ds) do {                                                      \
    gload16(b1[4] + (size_t)(kt) * 64, Bs + (ds) * 12288 + 4 * 2048 + doff);   \
    gload16(b1[5] + (size_t)(kt) * 64, Bs + (ds) * 12288 + 5 * 2048 + doff);   \
    gload16(a1[0] + (size_t)(kt) * 64, As + (ds) * 8192 + 0 * 2048 + doff);    \
    gload16(a1[1] + (size_t)(kt) * 64, As + (ds) * 8192 + 1 * 2048 + doff); } while (0)
#define I2_1(kt, ds) do {                                                      \
    gload16(a1[2] + (size_t)(kt) * 64, As + (ds) * 8192 + 2 * 2048 + doff);    \
    gload16(a1[3] + (size_t)(kt) * 64, As + (ds) * 8192 + 3 * 2048 + doff); } while (0)
// phase2 issue groups (k2 in units of 64 along K=256)
#define I0_2(k2, ds) do {                                                      \
    gload16(b2[0] + (size_t)(k2) * 64, Bs + (ds) * 12288 + 0 * 2048 + doff);   \
    gload16(b2[1] + (size_t)(k2) * 64, Bs + (ds) * 12288 + 1 * 2048 + doff);   \
    gload16(b2[2] + (size_t)(k2) * 64, Bs + (ds) * 12288 + 2 * 2048 + doff);   \
    gload16(b2[3] + (size_t)(k2) * 64, Bs + (ds) * 12288 + 3 * 2048 + doff); } while (0)
#define I1_2(k2, ds) do {                                                      \
    gload16(b2[4] + (size_t)(k2) * 64, Bs + (ds) * 12288 + 4 * 2048 + doff);   \
    gload16(b2[5] + (size_t)(k2) * 64, Bs + (ds) * 12288 + 5 * 2048 + doff);   \
    gload16(a2[0] + (size_t)(k2) * 64, As + (ds) * 8192 + 0 * 2048 + doff);    \
    gload16(a2[1] + (size_t)(k2) * 64, As + (ds) * 8192 + 1 * 2048 + doff); } while (0)
#define I2_2(k2, ds) do {                                                      \
    gload16(a2[2] + (size_t)(k2) * 64, As + (ds) * 8192 + 2 * 2048 + doff);    \
    gload16(a2[3] + (size_t)(k2) * 64, As + (ds) * 8192 + 3 * 2048 + doff); } while (0)

// One K-tile: P0 {I0, vmcnt(W0), bar, av+bv(n0) kb0, 12 MFMA}
//             P1 {I1, bv(n1) kb0, 12 MFMA}
//             P2 {I2, av+bv(n0) kb1, 12 MFMA}
//             P3 {bv(n1) kb1, 12 MFMA, bar}
#define KSTEP(slot_, I0, W0, I1, I2, NT) do {                                  \
    const unsigned short* aS = As + (slot_) * 8192;                            \
    const unsigned short* bS = Bs + (slot_) * 12288;                           \
    I0;                                                                        \
    asm volatile("s_waitcnt vmcnt(" W0 ")" ::: "memory");                      \
    __builtin_amdgcn_s_barrier();                                              \
    _Pragma("unroll") for (int m_ = 0; m_ < 4; ++m_) av[m_] = LDA(m_, kb0);    \
    _Pragma("unroll") for (int s_ = 0; s_ < 3; ++s_) bv[s_] = LDB(s_, 0, kb0); \
    MFMA12(0, NT);                                                             \
    I1;                                                                        \
    _Pragma("unroll") for (int s_ = 0; s_ < 3; ++s_) bv[s_] = LDB(s_, 1, kb0); \
    MFMA12(1, NT);                                                             \
    I2;                                                                        \
    _Pragma("unroll") for (int m_ = 0; m_ < 4; ++m_) av[m_] = LDA(m_, kb1);    \
    _Pragma("unroll") for (int s_ = 0; s_ < 3; ++s_) bv[s_] = LDB(s_, 0, kb1); \
    MFMA12(0, NT);                                                             \
    _Pragma("unroll") for (int s_ = 0; s_ < 3; ++s_) bv[s_] = LDB(s_, 1, kb1); \
    MFMA12(1, NT);                                                             \
    __builtin_amdgcn_s_barrier();                                              \
} while (0)

__global__ __launch_bounds__(256, 2)
void gru_fused(const unsigned short* __restrict__ Xb,    // [8192][1024] bf16
               const unsigned short* __restrict__ Wirb,  // [6144][1024] bf16
               const unsigned short* __restrict__ Hbb,   // [8192][2048] bf16
               const unsigned short* __restrict__ Whb,   // [8][768][256] bf16
               const float* __restrict__ b_ir_lin,       // [6144]
               const float* __restrict__ b_ir,           // [6144]
               const float* __restrict__ b_hr,           // [6144]
               const float* __restrict__ Hf,             // [8192][2048] f32
               float* __restrict__ out) {                // [8192][2048] f32
    constexpr int K1 = 1024, H = 2048;
    __shared__ unsigned short lds[2 * 8192 + 2 * 12288];   // 80 KiB
    unsigned short* const As = lds;
    unsigned short* const Bs = lds + 2 * 8192;

    const int tid  = threadIdx.x;
    const int lane = tid & 63;
    const int w    = tid >> 6;   // 0..3
    const int wm   = w >> 1;     // 0..1 (64-row half)
    const int wn   = w & 1;      // 0..1 (32-col half)

    // Grid: 2048 = 8 kb (XCD-exclusive) x 64 bm x 4 hsub (hsub innermost).
    const int bid  = blockIdx.x;
    const int kb   = bid & 7;
    const int idx  = bid >> 3;          // 0..255
    const int bm   = (idx >> 2) * 128;
    const int hsub = idx & 3;
    const int hcb  = kb * 256 + hsub * 64;   // h-column base

    // ---- staging sources (inverse-swizzled global, linear LDS dest)
    const int srow  = tid >> 3;                 // 0..31 (row within 32-row chunk)
    const int chunk = (tid & 7) ^ (srow & 7);   // T2 XOR involution
    const int scol  = chunk * 8;
    const int doff  = tid * 8;                  // element offset within a chunk
    const unsigned short* a1[4];
    const unsigned short* a2[4];
    #pragma unroll
    for (int q = 0; q < 4; ++q) {
        a1[q] = Xb  + (size_t)(bm + q * 32 + srow) * K1 + scol;
        a2[q] = Hbb + (size_t)(bm + q * 32 + srow) * H + kb * 256 + scol;
    }
    const unsigned short* b1[6];
    const unsigned short* b2[6];
    #pragma unroll
    for (int q = 0; q < 6; ++q) {
        const int s  = q >> 1;
        const int rr = (q & 1) * 32 + srow;
        b1[q] = Wirb + (size_t)(s * 2048 + hcb + rr) * K1 + scol;
        b2[q] = Whb + (size_t)kb * 196608 + (size_t)(s * 256 + hsub * 64 + rr) * 256 + scol;
    }

    // ---- fragment read offsets (swizzled reads, rows are 128 B)
    const int fr  = lane & 15;
    const int k0e = (lane >> 4) * 8;
    const int mfr = (fr & 7) << 4;
    const int kb0 = ((k0e * 2) ^ mfr) >> 1;
    const int kb1 = (((k0e * 2) + 64) ^ mfr) >> 1;

    f32x4 acc[4][4][2] = {};   // [group][m-frag][n-frag]
    bf16x8 av[4], bv[3];

    // ---- prologue: tile 0 (phase1)
    I0_1(0, 0); I1_1(0, 0); I2_1(0, 0);

    // ---- phase1: tiles 0..14 (issue t+1, phase1)
    #pragma unroll 1
    for (int t = 0; t < 15; ++t) {
        const int sl = t & 1, nx = sl ^ 1;
        KSTEP(sl, I0_1(t + 1, nx), "4", I1_1(t + 1, nx), I2_1(t + 1, nx), 2);
    }
    // ---- bridge: compute tile 15 (phase1), issue tile 16 (phase2, k2=0)
    KSTEP(1, I0_2(0, 0), "4", I1_2(0, 0), I2_2(0, 0), 2);
    // ---- phase2: tiles 16..18 (issue k2 = t-15)
    #pragma unroll 1
    for (int t = 16; t < 19; ++t) {
        const int sl = t & 1, nx = sl ^ 1;
        KSTEP(sl, I0_2(t - 15, nx), "4", I1_2(t - 15, nx), I2_2(t - 15, nx), 3);
    }
    // ---- peel: tile 19, drain
    KSTEP(1, ((void)0), "0", ((void)0), ((void)0), 3);

    // ---- gate epilogue
    const int rq = (lane >> 4) * 4;
    #pragma unroll
    for (int n = 0; n < 2; ++n) {
        const int hcol = hcb + wn * 32 + n * 16 + fr;   // 0..2047
        const int lcol = hcol & 255;                    // within diagonal block
        const float bir0 = b_ir_lin[hcol]        + b_ir[hcol];
        const float bir1 = b_ir_lin[2048 + hcol] + b_ir[2048 + hcol];
        const float bir2 = b_ir_lin[4096 + hcol] + b_ir[4096 + hcol];
        const float bhr0 = b_hr[kb * 768 + lcol];
        const float bhr1 = b_hr[kb * 768 + 256 + lcol];
        const float bhr2 = b_hr[kb * 768 + 512 + lcol];
        #pragma unroll
        for (int mi = 0; mi < 4; ++mi) {
            #pragma unroll
            for (int r = 0; r < 4; ++r) {
                const int row = bm + wm * 64 + mi * 16 + rq + r;
                const float pr = acc[0][mi][n][r] + bir0 + bhr0;
                const float pz = acc[1][mi][n][r] + bir1 + bhr1;
                const float xn = acc[2][mi][n][r] + bir2;
                const float hn = acc[3][mi][n][r] + bhr2;
                const float rg = sigmoidf_(pr);
                const float zg = sigmoidf_(pz);
                const float ng = tanhf_(xn + rg * hn);
                const float hv = Hf[(size_t)row * H + hcol];
                out[(size_t)row * H + hcol] = (1.0f - zg) * hv + zg * ng;
            }
        }
    }
}

// ---------------------------------------------------------------- launch
extern "C" void kernel_launch(void* const* d_in, const int* in_sizes, int n_in,
                              void* d_out, int out_size, void* d_ws, size_t ws_size,
                              hipStream_t stream) {
    const float* x        = (const float*)d_in[0];
    const float* h        = (const float*)d_in[1];
    const float* W_ir     = (const float*)d_in[2];
    const float* b_ir_lin = (const float*)d_in[3];
    const float* b_ir     = (const float*)d_in[4];
    const float* W_h      = (const float*)d_in[5];
    const float* b_hr     = (const float*)d_in[6];
    float* out = (float*)d_out;

    char* ws = (char*)d_ws;
    unsigned short* xb   = (unsigned short*)(ws);               // 16 MiB
    unsigned short* wirb = (unsigned short*)(ws + 16777216);    // 12 MiB
    unsigned short* hb   = (unsigned short*)(ws + 29360128);    // 32 MiB
    unsigned short* whb  = (unsigned short*)(ws + 62914560);    //  3 MiB

    cast_f32_to_bf16<<<8192,  256, 0, stream>>>(x,    xb,   2097152);
    cast_f32_to_bf16<<<6144,  256, 0, stream>>>(W_ir, wirb, 1572864);
    cast_f32_to_bf16<<<16384, 256, 0, stream>>>(h,    hb,   4194304);
    cast_f32_to_bf16<<<1536,  256, 0, stream>>>(W_h,  whb,  393216);

    gru_fused<<<2048, 256, 0, stream>>>(xb, wirb, hb, whb,
                                        b_ir_lin, b_ir, b_hr, h, out);
}